// Round 1
// baseline (244.396 us; speedup 1.0000x reference)
//
#include <hip/hip_runtime.h>
#include <hip/hip_bf16.h>

// Problem: B=4, S=2048, D_IN=D_OUT=1024 causal attention, fp32 in/out.
#define BB 4
#define SS 2048
#define DD 1024

typedef __attribute__((ext_vector_type(8))) short bf16x8;
typedef __attribute__((ext_vector_type(4))) float f32x4;

__device__ __forceinline__ ushort f2bf(float f) {
  unsigned u = __float_as_uint(f);
  unsigned r = (u + 0x7fffu + ((u >> 16) & 1u)) >> 16;  // RNE
  return (ushort)r;
}

__device__ __forceinline__ void gload_lds16(const void* g, void* l) {
  __builtin_amdgcn_global_load_lds(
      (const __attribute__((address_space(1))) void*)g,
      (__attribute__((address_space(3))) void*)l, 16, 0, 0);
}

// ---------------------------------------------------------------- cast x -> bf16
__global__ __launch_bounds__(256) void cast_x_kernel(const float* __restrict__ x,
                                                     ushort* __restrict__ xb) {
  const int i = blockIdx.x * 256 + threadIdx.x;  // 8 elems per thread
  const float4 a = ((const float4*)x)[2 * i];
  const float4 b = ((const float4*)x)[2 * i + 1];
  ushort4 o0, o1;
  o0.x = f2bf(a.x); o0.y = f2bf(a.y); o0.z = f2bf(a.z); o0.w = f2bf(a.w);
  o1.x = f2bf(b.x); o1.y = f2bf(b.y); o1.z = f2bf(b.z); o1.w = f2bf(b.w);
  ((ushort4*)xb)[2 * i] = o0;
  ((ushort4*)xb)[2 * i + 1] = o1;
}

// ------------------------------------------- cast + transpose W [K,N] -> Wt [N,K] bf16
__global__ __launch_bounds__(256) void cast_transpose_w(const float* __restrict__ W0,
                                                        const float* __restrict__ W1,
                                                        const float* __restrict__ W2,
                                                        ushort* __restrict__ Wt) {
  const float* W = blockIdx.z == 0 ? W0 : (blockIdx.z == 1 ? W1 : W2);
  ushort* O = Wt + (size_t)blockIdx.z * DD * DD;
  __shared__ ushort t[32][33];
  const int n0 = blockIdx.x * 32, k0 = blockIdx.y * 32;
  const int tx = threadIdx.x, ty = threadIdx.y;  // (32,8)
#pragma unroll
  for (int j = 0; j < 4; j++) {
    int k = k0 + ty + j * 8;
    t[ty + j * 8][tx] = f2bf(W[(size_t)k * DD + n0 + tx]);
  }
  __syncthreads();
#pragma unroll
  for (int j = 0; j < 4; j++) {
    int n = ty + j * 8;
    O[(size_t)(n0 + n) * DD + k0 + tx] = t[tx][n];
  }
}

// ------------------------------------------- transpose V [S,D] -> Vt [D,S] per batch (bf16)
__global__ __launch_bounds__(256) void transpose_v(const ushort* __restrict__ V,
                                                   ushort* __restrict__ Vt) {
  const int b = blockIdx.z;
  const ushort* Vb = V + (size_t)b * SS * DD;
  ushort* Ob = Vt + (size_t)b * DD * SS;
  __shared__ ushort t[32][33];
  const int d0 = blockIdx.x * 32, s0 = blockIdx.y * 32;
  const int tx = threadIdx.x, ty = threadIdx.y;  // (32,8)
#pragma unroll
  for (int j = 0; j < 4; j++) {
    int s = s0 + ty + j * 8;
    t[ty + j * 8][tx] = Vb[(size_t)s * DD + d0 + tx];
  }
  __syncthreads();
#pragma unroll
  for (int j = 0; j < 4; j++) {
    int d = ty + j * 8;
    Ob[(size_t)(d0 + d) * SS + s0 + tx] = t[tx][d];
  }
}

// ---------------------------------------------------------------- MFMA GEMM
// C[M,N] = A[M,K](bf16,row-major) @ Bt[N,K](bf16,row-major)^T
// 128x128 tile, 4 waves (2x2), BK=32, 16x16x32 bf16 MFMA, global_load_lds staging.
template <bool OUT_BF16, bool CAUSAL, bool KCLIP>
__global__ __launch_bounds__(256) void gemm_bt(const ushort* __restrict__ A, int lda, size_t strA,
                                               const ushort* __restrict__ Bt, int ldb, size_t strB,
                                               void* __restrict__ C, int ldc, size_t strC,
                                               int K) {
  const int nb = blockIdx.x, mb = blockIdx.y, bz = blockIdx.z;
  if (CAUSAL && nb > mb) return;  // tile fully above diagonal: softmax never reads it
  const ushort* Ab = A + (size_t)bz * strA;
  const ushort* Bb = Bt + (size_t)bz * strB;

  __shared__ ushort sA[128 * 32];
  __shared__ ushort sB[128 * 32];

  const int tid = threadIdx.x;
  const int lane = tid & 63, wid = tid >> 6;
  const int wr = wid >> 1, wc = wid & 1;   // wave 2x2 -> 64x64 each
  const int fr = lane & 15;                // fragment row (A) / col (B)
  const int fk = (lane >> 4) * 8;          // fragment k offset
  const int rbase = (lane >> 4) * 4;       // C/D row base (verified m89/m91 mapping)

  // staging: element l in [0,512): 16B each; row = l/4, col16 = l%4
  const int l0 = tid, l1 = tid + 256;
  const int ar0 = l0 >> 2, ac0 = (l0 & 3) * 8;
  const int ar1 = l1 >> 2, ac1 = (l1 & 3) * 8;
  const size_t aRow0 = (size_t)(mb * 128 + ar0) * lda;
  const size_t aRow1 = (size_t)(mb * 128 + ar1) * lda;
  const size_t bRow0 = (size_t)(nb * 128 + ar0) * ldb;
  const size_t bRow1 = (size_t)(nb * 128 + ar1) * ldb;

  int kEnd = KCLIP ? (mb + 1) * 128 : K;  // PV: P[.,k]=0 for k > row block end
  if (kEnd > K) kEnd = K;

  f32x4 acc[4][4] = {};

  for (int k0 = 0; k0 < kEnd; k0 += 32) {
    __syncthreads();
    gload_lds16(Ab + aRow0 + k0 + ac0, &sA[l0 * 8]);
    gload_lds16(Ab + aRow1 + k0 + ac1, &sA[l1 * 8]);
    gload_lds16(Bb + bRow0 + k0 + ac0, &sB[l0 * 8]);
    gload_lds16(Bb + bRow1 + k0 + ac1, &sB[l1 * 8]);
    __syncthreads();

    bf16x8 af[4], bfr[4];
#pragma unroll
    for (int i = 0; i < 4; i++)
      af[i] = *(const bf16x8*)&sA[(wr * 64 + i * 16 + fr) * 32 + fk];
#pragma unroll
    for (int i = 0; i < 4; i++)
      bfr[i] = *(const bf16x8*)&sB[(wc * 64 + i * 16 + fr) * 32 + fk];
#pragma unroll
    for (int mi = 0; mi < 4; mi++)
#pragma unroll
      for (int ni = 0; ni < 4; ni++)
        acc[mi][ni] =
            __builtin_amdgcn_mfma_f32_16x16x32_bf16(af[mi], bfr[ni], acc[mi][ni], 0, 0, 0);
  }

  const int nbase = nb * 128 + wc * 64 + fr;
  const int mrow0 = mb * 128 + wr * 64 + rbase;
  if (OUT_BF16) {
    ushort* Cb = (ushort*)C + (size_t)bz * strC;
#pragma unroll
    for (int mi = 0; mi < 4; mi++)
#pragma unroll
      for (int r = 0; r < 4; r++) {
        size_t rowoff = (size_t)(mrow0 + mi * 16 + r) * ldc;
#pragma unroll
        for (int ni = 0; ni < 4; ni++) Cb[rowoff + nbase + ni * 16] = f2bf(acc[mi][ni][r]);
      }
  } else {
    float* Cb = (float*)C + (size_t)bz * strC;
#pragma unroll
    for (int mi = 0; mi < 4; mi++)
#pragma unroll
      for (int r = 0; r < 4; r++) {
        size_t rowoff = (size_t)(mrow0 + mi * 16 + r) * ldc;
#pragma unroll
        for (int ni = 0; ni < 4; ni++) Cb[rowoff + nbase + ni * 16] = acc[mi][ni][r];
      }
  }
}

// ---------------------------------------------------------------- causal row softmax
// Sc: [B*S, S] f32 raw scores (valid only for col<=row-in-batch). P: [B*S, S] bf16.
__global__ __launch_bounds__(256) void softmax_causal(const float* __restrict__ Sc,
                                                      ushort* __restrict__ P) {
  const int row = blockIdx.x;        // b*S + r
  const int r = row & (SS - 1);
  const float* srow = Sc + (size_t)row * SS;
  ushort* prow = P + (size_t)row * SS;
  const int tid = threadIdx.x;
  const float scale = 0.03125f;  // 1/sqrt(1024)

  float mx = -3.0e38f;
  for (int c4 = tid; c4 < SS / 4; c4 += 256) {
    float4 v = ((const float4*)srow)[c4];
    int c = c4 * 4;
    if (c + 3 <= r) {
      mx = fmaxf(mx, fmaxf(fmaxf(v.x, v.y), fmaxf(v.z, v.w)));
    } else if (c <= r) {
      mx = fmaxf(mx, v.x);
      if (c + 1 <= r) mx = fmaxf(mx, v.y);
      if (c + 2 <= r) mx = fmaxf(mx, v.z);
    }
  }
  const int lane = tid & 63, wid = tid >> 6;
  __shared__ float redm[4], reds[4];
#pragma unroll
  for (int off = 32; off > 0; off >>= 1) mx = fmaxf(mx, __shfl_down(mx, off));
  if (lane == 0) redm[wid] = mx;
  __syncthreads();
  mx = fmaxf(fmaxf(redm[0], redm[1]), fmaxf(redm[2], redm[3]));

  float sum = 0.f;
  for (int c4 = tid; c4 < SS / 4; c4 += 256) {
    float4 v = ((const float4*)srow)[c4];
    int c = c4 * 4;
    if (c + 3 <= r) {
      sum += __expf((v.x - mx) * scale) + __expf((v.y - mx) * scale) +
             __expf((v.z - mx) * scale) + __expf((v.w - mx) * scale);
    } else if (c <= r) {
      sum += __expf((v.x - mx) * scale);
      if (c + 1 <= r) sum += __expf((v.y - mx) * scale);
      if (c + 2 <= r) sum += __expf((v.z - mx) * scale);
    }
  }
#pragma unroll
  for (int off = 32; off > 0; off >>= 1) sum += __shfl_down(sum, off);
  if (lane == 0) reds[wid] = sum;
  __syncthreads();
  sum = reds[0] + reds[1] + reds[2] + reds[3];
  const float inv = 1.0f / sum;

  for (int c4 = tid; c4 < SS / 4; c4 += 256) {
    float4 v = ((const float4*)srow)[c4];
    int c = c4 * 4;
    ushort4 o;
    o.x = (c <= r) ? f2bf(__expf((v.x - mx) * scale) * inv) : (ushort)0;
    o.y = (c + 1 <= r) ? f2bf(__expf((v.y - mx) * scale) * inv) : (ushort)0;
    o.z = (c + 2 <= r) ? f2bf(__expf((v.z - mx) * scale) * inv) : (ushort)0;
    o.w = (c + 3 <= r) ? f2bf(__expf((v.w - mx) * scale) * inv) : (ushort)0;
    ((ushort4*)prow)[c4] = o;
  }
}

// ---------------------------------------------------------------- launch
extern "C" void kernel_launch(void* const* d_in, const int* in_sizes, int n_in,
                              void* d_out, int out_size, void* d_ws, size_t ws_size,
                              hipStream_t stream) {
  const float* x = (const float*)d_in[0];
  const float* Wq = (const float*)d_in[1];
  const float* Wk = (const float*)d_in[2];
  const float* Wv = (const float*)d_in[3];

  char* ws = (char*)d_ws;
  // layout (bytes):
  //   xb  @ 0          16,777,216   (B*S*D bf16)        [reused later by Vt]
  //   Wt  @ 16777216    6,291,456   (3 x D*D bf16, transposed)
  //   Q   @ 23068672   16,777,216                       [reused later by P]
  //   K   @ 39845888   16,777,216                       [reused later by P]
  //   V   @ 56623104   16,777,216
  //   Sc  @ 73400320   67,108,864   (B*S*S f32)
  // total 140,509,184
  ushort* xb = (ushort*)(ws);
  ushort* Wt = (ushort*)(ws + 16777216);
  ushort* Q = (ushort*)(ws + 23068672);
  ushort* Kb = (ushort*)(ws + 39845888);
  ushort* Vb = (ushort*)(ws + 56623104);
  float* Sc = (float*)(ws + 73400320);
  ushort* P = (ushort*)(ws + 23068672);   // overlays Q,K (dead after scores GEMM)
  ushort* Vt = (ushort*)(ws);             // overlays xb (dead after projections)

  const size_t SD = (size_t)SS * DD;  // 2M elems
  const size_t S2 = (size_t)SS * SS;  // 4M elems

  // 1. cast x -> bf16
  cast_x_kernel<<<(BB * SS * DD) / (256 * 8), 256, 0, stream>>>(x, xb);
  // 2. cast+transpose weights
  cast_transpose_w<<<dim3(DD / 32, DD / 32, 3), dim3(32, 8), 0, stream>>>(Wq, Wk, Wv, Wt);
  // 3. projections: [8192,1024] = xb @ Wt^T
  gemm_bt<true, false, false><<<dim3(DD / 128, (BB * SS) / 128, 1), 256, 0, stream>>>(
      xb, DD, 0, Wt + 0 * DD * DD, DD, 0, Q, DD, 0, DD);
  gemm_bt<true, false, false><<<dim3(DD / 128, (BB * SS) / 128, 1), 256, 0, stream>>>(
      xb, DD, 0, Wt + 1 * (size_t)DD * DD, DD, 0, Kb, DD, 0, DD);
  gemm_bt<true, false, false><<<dim3(DD / 128, (BB * SS) / 128, 1), 256, 0, stream>>>(
      xb, DD, 0, Wt + 2 * (size_t)DD * DD, DD, 0, Vb, DD, 0, DD);
  // 4. Vt = V^T per batch (xb now dead)
  transpose_v<<<dim3(DD / 32, SS / 32, BB), dim3(32, 8), 0, stream>>>(Vb, Vt);
  // 5. scores = Q @ K^T (f32, causal block skip)
  gemm_bt<false, true, false><<<dim3(SS / 128, SS / 128, BB), 256, 0, stream>>>(
      Q, DD, SD, Kb, DD, SD, Sc, SS, S2, DD);
  // 6. softmax rows -> P bf16 (overlays Q,K)
  softmax_causal<<<BB * SS, 256, 0, stream>>>(Sc, P);
  // 7. out = P @ Vt^T (f32 into d_out), k-clipped per row block
  gemm_bt<false, false, true><<<dim3(DD / 128, SS / 128, BB), 256, 0, stream>>>(
      P, SS, S2, Vt, SS, SD, d_out, DD, SD, SS);

  (void)in_sizes; (void)n_in; (void)out_size; (void)ws_size;
}

// Round 2
// 193.136 us; speedup vs baseline: 1.2654x; 1.2654x over previous
//
#include <hip/hip_runtime.h>
#include <hip/hip_bf16.h>

// B=4, S=2048, D=1024 causal attention, fp32 in/out, bf16 MFMA compute.
#define BB 4
#define SS 2048
#define DD 1024

typedef __attribute__((ext_vector_type(8))) short bf16x8;
typedef __attribute__((ext_vector_type(4))) float f32x4;

__device__ __forceinline__ ushort f2bf(float f) {
  unsigned u = __float_as_uint(f);
  unsigned r = (u + 0x7fffu + ((u >> 16) & 1u)) >> 16;  // RNE
  return (ushort)r;
}

__device__ __forceinline__ void gload_lds16(const void* g, void* l) {
  __builtin_amdgcn_global_load_lds(
      (const __attribute__((address_space(1))) void*)g,
      (__attribute__((address_space(3))) void*)l, 16, 0, 0);
}

// ---------------------------------------------------------------- cast x -> bf16
__global__ __launch_bounds__(256) void cast_x_kernel(const float* __restrict__ x,
                                                     ushort* __restrict__ xb) {
  const int i = blockIdx.x * 256 + threadIdx.x;  // 8 elems per thread
  const float4 a = ((const float4*)x)[2 * i];
  const float4 b = ((const float4*)x)[2 * i + 1];
  ushort4 o0, o1;
  o0.x = f2bf(a.x); o0.y = f2bf(a.y); o0.z = f2bf(a.z); o0.w = f2bf(a.w);
  o1.x = f2bf(b.x); o1.y = f2bf(b.y); o1.z = f2bf(b.z); o1.w = f2bf(b.w);
  ((ushort4*)xb)[2 * i] = o0;
  ((ushort4*)xb)[2 * i + 1] = o1;
}

// ------------------------------------------- cast + transpose W [K,N] -> Wt [N,K] bf16
__global__ __launch_bounds__(256) void cast_transpose_w(const float* __restrict__ W0,
                                                        const float* __restrict__ W1,
                                                        const float* __restrict__ W2,
                                                        ushort* __restrict__ Wt) {
  const float* W = blockIdx.z == 0 ? W0 : (blockIdx.z == 1 ? W1 : W2);
  ushort* O = Wt + (size_t)blockIdx.z * DD * DD;
  __shared__ ushort t[32][33];
  const int n0 = blockIdx.x * 32, k0 = blockIdx.y * 32;
  const int tx = threadIdx.x, ty = threadIdx.y;  // (32,8)
#pragma unroll
  for (int j = 0; j < 4; j++) {
    int k = k0 + ty + j * 8;
    t[ty + j * 8][tx] = f2bf(W[(size_t)k * DD + n0 + tx]);
  }
  __syncthreads();
#pragma unroll
  for (int j = 0; j < 4; j++) {
    int n = ty + j * 8;
    O[(size_t)(n0 + n) * DD + k0 + tx] = t[tx][n];
  }
}

// ------------------------------------------- transpose V [S,ldv slice] -> Vt [D,S] per batch
__global__ __launch_bounds__(256) void transpose_v(const ushort* __restrict__ V, int ldv,
                                                   ushort* __restrict__ Vt) {
  const int b = blockIdx.z;
  const ushort* Vb = V + (size_t)b * SS * ldv;
  ushort* Ob = Vt + (size_t)b * DD * SS;
  __shared__ ushort t[32][33];
  const int d0 = blockIdx.x * 32, s0 = blockIdx.y * 32;
  const int tx = threadIdx.x, ty = threadIdx.y;  // (32,8)
#pragma unroll
  for (int j = 0; j < 4; j++) {
    int s = s0 + ty + j * 8;
    t[ty + j * 8][tx] = Vb[(size_t)s * ldv + d0 + tx];
  }
  __syncthreads();
#pragma unroll
  for (int j = 0; j < 4; j++) {
    int d = ty + j * 8;
    Ob[(size_t)(d0 + d) * SS + s0 + tx] = t[tx][d];
  }
}

// ---------------------------------------------------------------- MFMA GEMM, counted-vmcnt
// C[M,N] = A[M,K](bf16 rm) @ Bt[N,K](bf16 rm)^T.  BK=64, 512 thr = 8 waves (2M x 4N).
// Double-buffered K-tiles; s_waitcnt vmcnt(L) (counted, not 0) + raw s_barrier; LDS
// row-XOR swizzle (byte ^= (row&7)<<4) via inverse-swizzled global source (rule #21).
template <int BM, int BN, bool CAUSAL, bool KCLIP, bool OUT_BF16>
__global__ __launch_bounds__(512) void gemm8(const ushort* __restrict__ A, int lda, size_t strA,
                                             const ushort* __restrict__ Bt, int ldb, size_t strB,
                                             void* __restrict__ C, int ldc, size_t strC, int K) {
  constexpr int LA = BM / 64;  // gload_lds16 per thread per A tile
  constexpr int LB = BN / 64;
  constexpr int FM = BM / 32;  // frag rows per wave (wave rows = BM/2)
  constexpr int FN = BN / 64;  // frag cols per wave (wave cols = BN/4)
  const int nb = blockIdx.x, mb = blockIdx.y, bz = blockIdx.z;
  if (CAUSAL && nb * BN > mb * BM + (BM - 1)) return;  // tile fully above diagonal

  __shared__ ushort lds[2][(BM + BN) * 64];
  const ushort* Ab = A + (size_t)bz * strA + (size_t)mb * BM * lda;
  const ushort* Bb = Bt + (size_t)bz * strB + (size_t)nb * BN * ldb;

  const int tid = threadIdx.x;
  const int lane = tid & 63;
  const int wid = tid >> 6;
  const int wr = wid >> 2, wc = wid & 3;
  const int fr = lane & 15, qq = lane >> 4;
  const int sx = (fr & 7) << 4;  // read-side swizzle (row&7 == fr&7 for all frag rows)

  int kEnd = KCLIP ? (mb + 1) * BM : K;
  if (kEnd > K) kEnd = K;
  const int NT = kEnd >> 6;

  auto stage = [&](int kt, int buf) {
    ushort* As = &lds[buf][0];
    ushort* Bs = &lds[buf][BM * 64];
    const ushort* ga = Ab + kt * 64;
    const ushort* gb = Bb + kt * 64;
#pragma unroll
    for (int j = 0; j < LA; j++) {
      int D = (j * 512 + tid) * 16;              // linear LDS dest byte
      int r = D >> 7;                            // tile row (128B rows)
      int cb = (D & 127) ^ ((r & 7) << 4);       // inverse-swizzled source col-byte
      gload_lds16(ga + (size_t)r * lda + (cb >> 1), (char*)As + D);
    }
#pragma unroll
    for (int j = 0; j < LB; j++) {
      int D = (j * 512 + tid) * 16;
      int r = D >> 7;
      int cb = (D & 127) ^ ((r & 7) << 4);
      gload_lds16(gb + (size_t)r * ldb + (cb >> 1), (char*)Bs + D);
    }
  };

  stage(0, 0);
  if (NT > 1) stage(1, 1);

  f32x4 acc[FM][FN] = {};

  for (int kt = 0; kt < NT; ++kt) {
    const int cur = kt & 1;
    if (kt < NT - 1) {
      // wait for tile kt's own loads (oldest L), keep tile kt+1's in flight
      if constexpr (LA + LB == 6) asm volatile("s_waitcnt vmcnt(6)" ::: "memory");
      else if constexpr (LA + LB == 4) asm volatile("s_waitcnt vmcnt(4)" ::: "memory");
      else asm volatile("s_waitcnt vmcnt(0)" ::: "memory");
    } else {
      asm volatile("s_waitcnt vmcnt(0)" ::: "memory");
    }
    __builtin_amdgcn_s_barrier();
    __builtin_amdgcn_sched_barrier(0);

    const char* As = (const char*)&lds[cur][0];
    const char* Bs = (const char*)&lds[cur][BM * 64];
    __builtin_amdgcn_s_setprio(1);
#pragma unroll
    for (int ks = 0; ks < 2; ++ks) {
      const int kb = ks * 64 + qq * 16;  // logical col-byte for this lane
      bf16x8 a[FM], b[FN];
#pragma unroll
      for (int i = 0; i < FM; i++) {
        int r = wr * (BM / 2) + i * 16 + fr;
        a[i] = *(const bf16x8*)(As + r * 128 + (kb ^ sx));
      }
#pragma unroll
      for (int j = 0; j < FN; j++) {
        int r = wc * (BN / 4) + j * 16 + fr;
        b[j] = *(const bf16x8*)(Bs + r * 128 + (kb ^ sx));
      }
#pragma unroll
      for (int i = 0; i < FM; i++)
#pragma unroll
        for (int j = 0; j < FN; j++)
          acc[i][j] = __builtin_amdgcn_mfma_f32_16x16x32_bf16(a[i], b[j], acc[i][j], 0, 0, 0);
    }
    __builtin_amdgcn_s_setprio(0);
    __builtin_amdgcn_s_barrier();          // all waves done reading lds[cur]
    __builtin_amdgcn_sched_barrier(0);
    if (kt + 2 < NT) stage(kt + 2, cur);   // safe to overwrite now; lands before kt+2
  }

  // epilogue: C/D mapping col=lane&15, row=(lane>>4)*4+reg (m89/m91)
  const int col0 = nb * BN + wc * (BN / 4) + fr;
  const int row00 = mb * BM + wr * (BM / 2) + qq * 4;
  if (OUT_BF16) {
    ushort* Cb = (ushort*)C + (size_t)bz * strC;
#pragma unroll
    for (int i = 0; i < FM; i++)
#pragma unroll
      for (int rr = 0; rr < 4; rr++) {
        size_t ro = (size_t)(row00 + i * 16 + rr) * ldc;
#pragma unroll
        for (int j = 0; j < FN; j++) Cb[ro + col0 + j * 16] = f2bf(acc[i][j][rr]);
      }
  } else {
    float* Cb = (float*)C + (size_t)bz * strC;
#pragma unroll
    for (int i = 0; i < FM; i++)
#pragma unroll
      for (int rr = 0; rr < 4; rr++) {
        size_t ro = (size_t)(row00 + i * 16 + rr) * ldc;
#pragma unroll
        for (int j = 0; j < FN; j++) Cb[ro + col0 + j * 16] = acc[i][j][rr];
      }
  }
}

// ---------------------------------------------------------------- causal row softmax
__global__ __launch_bounds__(256) void softmax_causal(const float* __restrict__ Sc,
                                                      ushort* __restrict__ P) {
  const int row = blockIdx.x;  // b*S + r
  const int r = row & (SS - 1);
  const float* srow = Sc + (size_t)row * SS;
  ushort* prow = P + (size_t)row * SS;
  const int tid = threadIdx.x;
  const float scale = 0.03125f;  // 1/sqrt(1024)

  float mx = -3.0e38f;
  for (int c4 = tid; c4 < SS / 4; c4 += 256) {
    float4 v = ((const float4*)srow)[c4];
    int c = c4 * 4;
    if (c + 3 <= r) {
      mx = fmaxf(mx, fmaxf(fmaxf(v.x, v.y), fmaxf(v.z, v.w)));
    } else if (c <= r) {
      mx = fmaxf(mx, v.x);
      if (c + 1 <= r) mx = fmaxf(mx, v.y);
      if (c + 2 <= r) mx = fmaxf(mx, v.z);
    }
  }
  const int lane = tid & 63, wid = tid >> 6;
  __shared__ float redm[4], reds[4];
#pragma unroll
  for (int off = 32; off > 0; off >>= 1) mx = fmaxf(mx, __shfl_down(mx, off));
  if (lane == 0) redm[wid] = mx;
  __syncthreads();
  mx = fmaxf(fmaxf(redm[0], redm[1]), fmaxf(redm[2], redm[3]));

  float sum = 0.f;
  for (int c4 = tid; c4 < SS / 4; c4 += 256) {
    float4 v = ((const float4*)srow)[c4];
    int c = c4 * 4;
    if (c + 3 <= r) {
      sum += __expf((v.x - mx) * scale) + __expf((v.y - mx) * scale) +
             __expf((v.z - mx) * scale) + __expf((v.w - mx) * scale);
    } else if (c <= r) {
      sum += __expf((v.x - mx) * scale);
      if (c + 1 <= r) sum += __expf((v.y - mx) * scale);
      if (c + 2 <= r) sum += __expf((v.z - mx) * scale);
    }
  }
#pragma unroll
  for (int off = 32; off > 0; off >>= 1) sum += __shfl_down(sum, off);
  if (lane == 0) reds[wid] = sum;
  __syncthreads();
  sum = reds[0] + reds[1] + reds[2] + reds[3];
  const float inv = 1.0f / sum;

  for (int c4 = tid; c4 < SS / 4; c4 += 256) {
    float4 v = ((const float4*)srow)[c4];
    int c = c4 * 4;
    ushort4 o;
    o.x = (c <= r) ? f2bf(__expf((v.x - mx) * scale) * inv) : (ushort)0;
    o.y = (c + 1 <= r) ? f2bf(__expf((v.y - mx) * scale) * inv) : (ushort)0;
    o.z = (c + 2 <= r) ? f2bf(__expf((v.z - mx) * scale) * inv) : (ushort)0;
    o.w = (c + 3 <= r) ? f2bf(__expf((v.w - mx) * scale) * inv) : (ushort)0;
    ((ushort4*)prow)[c4] = o;
  }
}

// ---------------------------------------------------------------- launch
extern "C" void kernel_launch(void* const* d_in, const int* in_sizes, int n_in,
                              void* d_out, int out_size, void* d_ws, size_t ws_size,
                              hipStream_t stream) {
  const float* x = (const float*)d_in[0];
  const float* Wq = (const float*)d_in[1];
  const float* Wk = (const float*)d_in[2];
  const float* Wv = (const float*)d_in[3];

  char* ws = (char*)d_ws;
  // layout (bytes):
  //   xb   @ 0          16,777,216  (B*S*D bf16)         [reused by Vt]
  //   Wt   @ 16777216    6,291,456  (3 x D*D bf16 = Bt[3072][1024])
  //   QKV  @ 23068672   50,331,648  ([8192][3072] bf16)  [reused by P]
  //   Sc   @ 73400320   67,108,864  (B*S*S f32)
  // total 140,509,184
  ushort* xb = (ushort*)(ws);
  ushort* Wt = (ushort*)(ws + 16777216);
  ushort* QKV = (ushort*)(ws + 23068672);
  float* Sc = (float*)(ws + 73400320);
  ushort* P = (ushort*)(ws + 23068672);  // overlays QKV (Q,K,V dead by then)
  ushort* Vt = (ushort*)(ws);            // overlays xb (dead after projection)

  const size_t SD = (size_t)SS * DD;      // 2M
  const size_t S2 = (size_t)SS * SS;      // 4M
  const size_t SQ = (size_t)SS * 3072;    // QKV batch stride

  // 1. cast x -> bf16
  cast_x_kernel<<<(BB * SS * DD) / (256 * 8), 256, 0, stream>>>(x, xb);
  // 2. cast+transpose weights -> Bt[3072][1024]
  cast_transpose_w<<<dim3(DD / 32, DD / 32, 3), dim3(32, 8), 0, stream>>>(Wq, Wk, Wv, Wt);
  // 3. fused QKV projection: [8192,3072] = xb @ Wt^T   (768 blocks)
  gemm8<256, 128, false, false, true><<<dim3(3072 / 128, (BB * SS) / 256, 1), 512, 0, stream>>>(
      xb, DD, 0, Wt, DD, 0, QKV, 3072, 0, DD);
  // 4. Vt = V^T per batch (xb dead)
  transpose_v<<<dim3(DD / 32, SS / 32, BB), dim3(32, 8), 0, stream>>>(QKV + 2048, 3072, Vt);
  // 5. scores = Q @ K^T (f32, causal block skip)   (288 active blocks)
  gemm8<256, 128, true, false, false><<<dim3(SS / 128, SS / 256, BB), 512, 0, stream>>>(
      QKV, 3072, SQ, QKV + 1024, 3072, SQ, Sc, SS, S2, DD);
  // 6. softmax rows -> P bf16 (overlays QKV)
  softmax_causal<<<BB * SS, 256, 0, stream>>>(Sc, P);
  // 7. out = P @ Vt^T (f32 into d_out), k-clipped   (512 blocks, 2 blocks/CU)
  gemm8<128, 128, false, true, false><<<dim3(DD / 128, SS / 128, BB), 512, 0, stream>>>(
      P, SS, S2, Vt, SS, SD, d_out, DD, SD, SS);

  (void)in_sizes; (void)n_in; (void)out_size; (void)ws_size;
}